// Round 9
// baseline (85.034 us; speedup 1.0000x reference)
//
#include <hip/hip_runtime.h>

// GradientCurvatureAttention: fused depthwise-conv + curvature + channel-softmax + scale.
// x: [B=16, C=128, H=128, W=128] fp32, NCHW. out: same shape.
//
// Round 9: R7 base (best: 63.9us, 2048 x (32,8) blocks, CGRP=8, CPW=16) plus:
//  - explicit 1-deep software pipeline: next channel's 3 row-loads are issued
//    before the current channel's score math (hides VMEM latency under VALU).
//  - wave-uniform row-edge branch: h is block-uniform, so the 8 row-mask muls
//    per iter run only in the 2 edge-row blocks (s_cbranch, no divergence).
// R8 (2 rows/thread) regressed: occupancy 37->21% swamped the FETCH savings.

#define GCA_B 16
#define GCA_C 128
#define GCA_H 128
#define GCA_W 128
#define CGRP  8            // channel groups (blockDim.y)
#define CPW   (GCA_C/CGRP) // 16 channels per group

__device__ __forceinline__ float gca_score9(float cpl, float cpc, float cpr,
                                            float cml, float cmc, float cmr,
                                            float cyl, float cyc, float cyr) {
    const float Gx  = cpl - cpr;                       // [1,2,1]v x [1,0,-1]h
    const float Gy  = fmaf(2.f, cmc, cml + cmr);       // [1,0,-1]v x [1,2,1]h
    const float Ixx = fmaf(-2.f, cpc, cpl + cpr);      // [1,2,1]v x [1,-2,1]h
    const float Ixy = cmr - cml;                       // [1,0,-1]v x [-1,0,1]h
    const float Iyy = fmaf(2.f, cyc, cyl + cyr);       // [1,-2,1]v x [1,2,1]h
    const float gy2 = Gy * Gy;
    const float g2e = fmaf(Gx, Gx, gy2 + 1e-6f);
    const float r   = rsqrtf(g2e);
    const float gm  = g2e * r;                         // sqrt(g2e)
    const float t   = Gx * Iyy;
    const float p   = Gy * Ixy;
    const float inner = fmaf(-2.f, p, t);              // Gx*Iyy - 2*Gy*Ixy
    const float q   = gy2 * Ixx;
    const float num = fmaf(Gx, inner, q);
    const float r3  = (r * r) * r;
    return fmaf(num, r3, gm);                          // grad_mag + curvature
}

__global__ __launch_bounds__(256) void gca_fused9(const float* __restrict__ x,
                                                  float* __restrict__ out) {
    const int tx = threadIdx.x;                 // 0..31 : pixel quad, w0 = 4*tx
    const int ty = threadIdx.y;                 // 0..7  : channel group

    // XCD swizzle: 2048 blocks (= B*H, h minor), 256 consecutive ids per XCD.
    const int id  = blockIdx.x;
    const int swz = ((id & 7) << 8) | (id >> 3);
    const int h   = swz & 127;
    const int b   = swz >> 7;

    const int w0 = tx * 4;
    const int c0 = ty * CPW;

    const int hm = (h > 0) ? h - 1 : 0;
    const int hp = (h < GCA_H - 1) ? h + 1 : GCA_H - 1;
    const bool edgeh = (h == 0) || (h == GCA_H - 1);
    const float mh0 = (h > 0) ? 1.f : 0.f;
    const float mh2 = (h < GCA_H - 1) ? 1.f : 0.f;
    const float mwA = (tx > 0) ? 1.f : 0.f;    // left halo exists
    const float mwB = (tx < 31) ? 1.f : 0.f;   // right halo exists

    const size_t plane = (size_t)GCA_H * GCA_W;
    const float* base = x   + ((size_t)b * GCA_C + c0) * plane;
    float* obase      = out + ((size_t)b * GCA_C + c0) * plane;

    const int r0off = hm * GCA_W + w0;
    const int r1off = h  * GCA_W + w0;
    const int r2off = hp * GCA_W + w0;

    float4 s[CPW];                       // scores, then exp values
    float4 lmax = make_float4(-3.0e38f, -3.0e38f, -3.0e38f, -3.0e38f);

    // Software-pipelined pass 1: loads for iter i+1 issued before math of i.
    float4 v0 = *(const float4*)(base + r0off);
    float4 v1 = *(const float4*)(base + r1off);
    float4 v2 = *(const float4*)(base + r2off);

    #pragma unroll
    for (int i = 0; i < CPW; ++i) {
        float4 n0, n1, n2;
        if (i + 1 < CPW) {
            const float* pn = base + (size_t)(i + 1) * plane;
            n0 = *(const float4*)(pn + r0off);
            n1 = *(const float4*)(pn + r1off);
            n2 = *(const float4*)(pn + r2off);
        } else {
            n0 = v0; n1 = v1; n2 = v2;
        }

        // Row-edge masks only in the two edge-row blocks (wave-uniform branch).
        if (edgeh) {
            v0.x *= mh0; v0.y *= mh0; v0.z *= mh0; v0.w *= mh0;
            v2.x *= mh2; v2.y *= mh2; v2.z *= mh2; v2.w *= mh2;
        }

        // Own column sums for cols w0..w0+3 (A..D).
        const float cpA = fmaf(2.f, v1.x, v0.x + v2.x);
        const float cmA = v0.x - v2.x;
        const float cyA = fmaf(-4.f, v1.x, cpA);
        const float cpB = fmaf(2.f, v1.y, v0.y + v2.y);
        const float cmB = v0.y - v2.y;
        const float cyB = fmaf(-4.f, v1.y, cpB);
        const float cpC = fmaf(2.f, v1.z, v0.z + v2.z);
        const float cmC = v0.z - v2.z;
        const float cyC = fmaf(-4.f, v1.z, cpC);
        const float cpD = fmaf(2.f, v1.w, v0.w + v2.w);
        const float cmD = v0.w - v2.w;
        const float cyD = fmaf(-4.f, v1.w, cpD);

        // Halo column sums from neighbor lanes (row masks already applied).
        const float cpL = __shfl_up(cpD, 1) * mwA;
        const float cmL = __shfl_up(cmD, 1) * mwA;
        const float cyL = __shfl_up(cyD, 1) * mwA;
        const float cpR = __shfl_down(cpA, 1) * mwB;
        const float cmR = __shfl_down(cmA, 1) * mwB;
        const float cyR = __shfl_down(cyA, 1) * mwB;

        float4 sc;
        sc.x = gca_score9(cpL, cpA, cpB,  cmL, cmA, cmB,  cyL, cyA, cyB);
        sc.y = gca_score9(cpA, cpB, cpC,  cmA, cmB, cmC,  cyA, cyB, cyC);
        sc.z = gca_score9(cpB, cpC, cpD,  cmB, cmC, cmD,  cyB, cyC, cyD);
        sc.w = gca_score9(cpC, cpD, cpR,  cmC, cmD, cmR,  cyC, cyD, cyR);
        s[i] = sc;
        lmax.x = fmaxf(lmax.x, sc.x);
        lmax.y = fmaxf(lmax.y, sc.y);
        lmax.z = fmaxf(lmax.z, sc.z);
        lmax.w = fmaxf(lmax.w, sc.w);

        v0 = n0; v1 = n1; v2 = n2;
    }

    // Cross-group softmax reduction (per pixel, over the 8 channel groups).
    __shared__ float4 redmax[CGRP][32];
    __shared__ float4 redsum[CGRP][32];

    redmax[ty][tx] = lmax;
    __syncthreads();
    float4 gmax = make_float4(-3.0e38f, -3.0e38f, -3.0e38f, -3.0e38f);
    #pragma unroll
    for (int g = 0; g < CGRP; ++g) {
        const float4 m = redmax[g][tx];
        gmax.x = fmaxf(gmax.x, m.x);
        gmax.y = fmaxf(gmax.y, m.y);
        gmax.z = fmaxf(gmax.z, m.z);
        gmax.w = fmaxf(gmax.w, m.w);
    }

    float4 lsum = make_float4(0.f, 0.f, 0.f, 0.f);
    #pragma unroll
    for (int i = 0; i < CPW; ++i) {
        float4 e;
        e.x = __expf(s[i].x - gmax.x);
        e.y = __expf(s[i].y - gmax.y);
        e.z = __expf(s[i].z - gmax.z);
        e.w = __expf(s[i].w - gmax.w);
        s[i] = e;
        lsum.x += e.x; lsum.y += e.y; lsum.z += e.z; lsum.w += e.w;
    }
    redsum[ty][tx] = lsum;
    __syncthreads();
    float4 tot = make_float4(0.f, 0.f, 0.f, 0.f);
    #pragma unroll
    for (int g = 0; g < CGRP; ++g) {
        const float4 sm = redsum[g][tx];
        tot.x += sm.x; tot.y += sm.y; tot.z += sm.z; tot.w += sm.w;
    }
    const float invx = 1.f / tot.x, invy = 1.f / tot.y;
    const float invz = 1.f / tot.z, invw = 1.f / tot.w;

    // Epilogue: out = (softmax + 1) * x; center row reloaded (L2-resident).
    #pragma unroll
    for (int i = 0; i < CPW; ++i) {
        const float4 xv = *(const float4*)(base + (size_t)i * plane + r1off);
        float4 o;
        o.x = fmaf(s[i].x * invx, xv.x, xv.x);
        o.y = fmaf(s[i].y * invy, xv.y, xv.y);
        o.z = fmaf(s[i].z * invz, xv.z, xv.z);
        o.w = fmaf(s[i].w * invw, xv.w, xv.w);
        *(float4*)(obase + (size_t)i * plane + r1off) = o;
    }
}

extern "C" void kernel_launch(void* const* d_in, const int* in_sizes, int n_in,
                              void* d_out, int out_size, void* d_ws, size_t ws_size,
                              hipStream_t stream) {
    (void)in_sizes; (void)n_in; (void)d_ws; (void)ws_size; (void)out_size;
    const float* x = (const float*)d_in[0];
    float* out = (float*)d_out;
    dim3 block(32, CGRP, 1);
    dim3 grid(GCA_B * GCA_H, 1, 1);   // 2048 blocks, swizzled in-kernel
    gca_fused9<<<grid, block, 0, stream>>>(x, out);
}

// Round 10
// 65.057 us; speedup vs baseline: 1.3071x; 1.3071x over previous
//
#include <hip/hip_runtime.h>

// GradientCurvatureAttention: fused depthwise-conv + curvature + channel-softmax + scale.
// x: [B=16, C=128, H=128, W=128] fp32, NCHW. out: same shape.
//
// Round 10: R7 base (best: 63.9us) + paired channel iterations: 6 independent
// row-loads issued per loop body (2 channels x 3 rows) before either channel's
// math -> 2x memory-level parallelism per wave, no rotation registers, no
// in-loop branch (R9's explicit pipeline blew VGPR 64->184 and regressed).

#define GCA_B 16
#define GCA_C 128
#define GCA_H 128
#define GCA_W 128
#define CGRP  8            // channel groups (blockDim.y)
#define CPW   (GCA_C/CGRP) // 16 channels per group

__device__ __forceinline__ float gca_score10(float cpl, float cpc, float cpr,
                                             float cml, float cmc, float cmr,
                                             float cyl, float cyc, float cyr) {
    const float Gx  = cpl - cpr;                       // [1,2,1]v x [1,0,-1]h
    const float Gy  = fmaf(2.f, cmc, cml + cmr);       // [1,0,-1]v x [1,2,1]h
    const float Ixx = fmaf(-2.f, cpc, cpl + cpr);      // [1,2,1]v x [1,-2,1]h
    const float Ixy = cmr - cml;                       // [1,0,-1]v x [-1,0,1]h
    const float Iyy = fmaf(2.f, cyc, cyl + cyr);       // [1,-2,1]v x [1,2,1]h
    const float gy2 = Gy * Gy;
    const float g2e = fmaf(Gx, Gx, gy2 + 1e-6f);
    const float r   = rsqrtf(g2e);
    const float gm  = g2e * r;                         // sqrt(g2e)
    const float t   = Gx * Iyy;
    const float p   = Gy * Ixy;
    const float inner = fmaf(-2.f, p, t);              // Gx*Iyy - 2*Gy*Ixy
    const float q   = gy2 * Ixx;
    const float num = fmaf(Gx, inner, q);
    const float r3  = (r * r) * r;
    return fmaf(num, r3, gm);                          // grad_mag + curvature
}

// One channel's 4 scores from 3 masked row-vectors.
#define GCA_CHAN_SCORES(v0, v1, v2, scv, lmaxv)                                \
    {                                                                          \
        const float cpA = fmaf(2.f, (v1).x, (v0).x + (v2).x);                  \
        const float cmA = (v0).x - (v2).x;                                     \
        const float cyA = fmaf(-4.f, (v1).x, cpA);                             \
        const float cpB = fmaf(2.f, (v1).y, (v0).y + (v2).y);                  \
        const float cmB = (v0).y - (v2).y;                                     \
        const float cyB = fmaf(-4.f, (v1).y, cpB);                             \
        const float cpC = fmaf(2.f, (v1).z, (v0).z + (v2).z);                  \
        const float cmC = (v0).z - (v2).z;                                     \
        const float cyC = fmaf(-4.f, (v1).z, cpC);                             \
        const float cpD = fmaf(2.f, (v1).w, (v0).w + (v2).w);                  \
        const float cmD = (v0).w - (v2).w;                                     \
        const float cyD = fmaf(-4.f, (v1).w, cpD);                             \
        const float cpL = __shfl_up(cpD, 1) * mwA;                             \
        const float cmL = __shfl_up(cmD, 1) * mwA;                             \
        const float cyL = __shfl_up(cyD, 1) * mwA;                             \
        const float cpR = __shfl_down(cpA, 1) * mwB;                           \
        const float cmR = __shfl_down(cmA, 1) * mwB;                           \
        const float cyR = __shfl_down(cyA, 1) * mwB;                           \
        (scv).x = gca_score10(cpL, cpA, cpB, cmL, cmA, cmB, cyL, cyA, cyB);    \
        (scv).y = gca_score10(cpA, cpB, cpC, cmA, cmB, cmC, cyA, cyB, cyC);    \
        (scv).z = gca_score10(cpB, cpC, cpD, cmB, cmC, cmD, cyB, cyC, cyD);    \
        (scv).w = gca_score10(cpC, cpD, cpR, cmC, cmD, cmR, cyC, cyD, cyR);    \
        (lmaxv).x = fmaxf((lmaxv).x, (scv).x);                                 \
        (lmaxv).y = fmaxf((lmaxv).y, (scv).y);                                 \
        (lmaxv).z = fmaxf((lmaxv).z, (scv).z);                                 \
        (lmaxv).w = fmaxf((lmaxv).w, (scv).w);                                 \
    }

__global__ __launch_bounds__(256) void gca_fused10(const float* __restrict__ x,
                                                   float* __restrict__ out) {
    const int tx = threadIdx.x;                 // 0..31 : pixel quad, w0 = 4*tx
    const int ty = threadIdx.y;                 // 0..7  : channel group

    // XCD swizzle: 2048 blocks (= B*H, h minor), 256 consecutive ids per XCD.
    const int id  = blockIdx.x;
    const int swz = ((id & 7) << 8) | (id >> 3);
    const int h   = swz & 127;
    const int b   = swz >> 7;

    const int w0 = tx * 4;
    const int c0 = ty * CPW;

    const int hm = (h > 0) ? h - 1 : 0;
    const int hp = (h < GCA_H - 1) ? h + 1 : GCA_H - 1;
    const float mh0 = (h > 0) ? 1.f : 0.f;
    const float mh2 = (h < GCA_H - 1) ? 1.f : 0.f;
    const float mwA = (tx > 0) ? 1.f : 0.f;    // left halo exists
    const float mwB = (tx < 31) ? 1.f : 0.f;   // right halo exists

    const size_t plane = (size_t)GCA_H * GCA_W;
    const float* base = x   + ((size_t)b * GCA_C + c0) * plane;
    float* obase      = out + ((size_t)b * GCA_C + c0) * plane;

    const int r0off = hm * GCA_W + w0;
    const int r1off = h  * GCA_W + w0;
    const int r2off = hp * GCA_W + w0;

    float4 s[CPW];                       // scores, then exp values
    float4 lmax = make_float4(-3.0e38f, -3.0e38f, -3.0e38f, -3.0e38f);

    // Pass 1: conv + curvature scores, channels processed in PAIRS so the
    // 6 row-loads of both channels are in flight before either's math.
    #pragma unroll
    for (int i = 0; i < CPW; i += 2) {
        const float* pa = base + (size_t)i * plane;
        const float* pb = pa + plane;
        float4 a0 = *(const float4*)(pa + r0off);
        const float4 a1 = *(const float4*)(pa + r1off);
        float4 a2 = *(const float4*)(pa + r2off);
        float4 b0 = *(const float4*)(pb + r0off);
        const float4 b1 = *(const float4*)(pb + r1off);
        float4 b2 = *(const float4*)(pb + r2off);

        // Row-edge masks (identity except h=0 / h=127).
        a0.x *= mh0; a0.y *= mh0; a0.z *= mh0; a0.w *= mh0;
        a2.x *= mh2; a2.y *= mh2; a2.z *= mh2; a2.w *= mh2;
        b0.x *= mh0; b0.y *= mh0; b0.z *= mh0; b0.w *= mh0;
        b2.x *= mh2; b2.y *= mh2; b2.z *= mh2; b2.w *= mh2;

        GCA_CHAN_SCORES(a0, a1, a2, s[i],     lmax);
        GCA_CHAN_SCORES(b0, b1, b2, s[i + 1], lmax);
    }

    // Cross-group softmax reduction (per pixel, over the 8 channel groups).
    __shared__ float4 redmax[CGRP][32];
    __shared__ float4 redsum[CGRP][32];

    redmax[ty][tx] = lmax;
    __syncthreads();
    float4 gmax = make_float4(-3.0e38f, -3.0e38f, -3.0e38f, -3.0e38f);
    #pragma unroll
    for (int g = 0; g < CGRP; ++g) {
        const float4 m = redmax[g][tx];
        gmax.x = fmaxf(gmax.x, m.x);
        gmax.y = fmaxf(gmax.y, m.y);
        gmax.z = fmaxf(gmax.z, m.z);
        gmax.w = fmaxf(gmax.w, m.w);
    }

    float4 lsum = make_float4(0.f, 0.f, 0.f, 0.f);
    #pragma unroll
    for (int i = 0; i < CPW; ++i) {
        float4 e;
        e.x = __expf(s[i].x - gmax.x);
        e.y = __expf(s[i].y - gmax.y);
        e.z = __expf(s[i].z - gmax.z);
        e.w = __expf(s[i].w - gmax.w);
        s[i] = e;
        lsum.x += e.x; lsum.y += e.y; lsum.z += e.z; lsum.w += e.w;
    }
    redsum[ty][tx] = lsum;
    __syncthreads();
    float4 tot = make_float4(0.f, 0.f, 0.f, 0.f);
    #pragma unroll
    for (int g = 0; g < CGRP; ++g) {
        const float4 sm = redsum[g][tx];
        tot.x += sm.x; tot.y += sm.y; tot.z += sm.z; tot.w += sm.w;
    }
    const float invx = 1.f / tot.x, invy = 1.f / tot.y;
    const float invz = 1.f / tot.z, invw = 1.f / tot.w;

    // Epilogue: out = (softmax + 1) * x; center row reloaded (L2-resident).
    #pragma unroll
    for (int i = 0; i < CPW; ++i) {
        const float4 xv = *(const float4*)(base + (size_t)i * plane + r1off);
        float4 o;
        o.x = fmaf(s[i].x * invx, xv.x, xv.x);
        o.y = fmaf(s[i].y * invy, xv.y, xv.y);
        o.z = fmaf(s[i].z * invz, xv.z, xv.z);
        o.w = fmaf(s[i].w * invw, xv.w, xv.w);
        *(float4*)(obase + (size_t)i * plane + r1off) = o;
    }
}

extern "C" void kernel_launch(void* const* d_in, const int* in_sizes, int n_in,
                              void* d_out, int out_size, void* d_ws, size_t ws_size,
                              hipStream_t stream) {
    (void)in_sizes; (void)n_in; (void)d_ws; (void)ws_size; (void)out_size;
    const float* x = (const float*)d_in[0];
    float* out = (float*)d_out;
    dim3 block(32, CGRP, 1);
    dim3 grid(GCA_B * GCA_H, 1, 1);   // 2048 blocks, swizzled in-kernel
    gca_fused10<<<grid, block, 0, stream>>>(x, out);
}